// Round 2
// baseline (402.977 us; speedup 1.0000x reference)
//
#include <hip/hip_runtime.h>
#include <math.h>

#define TLEN 613376
#define NFR  600             // total frames
#define NB   2049            // bins
#define PI_F  3.14159265358979323846f
#define PI2_F 6.28318530717958647693f
#define PHYS(i) ((i) + ((i) >> 4))   // LDS pad

// periodic hann window
__device__ __forceinline__ float winf(int j) {
  return 0.5f - 0.5f * __cosf(1.5339807878856412e-3f * (float)j);  // 2*pi/4096
}

__device__ __forceinline__ float wsum_at(int m) {   // OLA window-power sum (edge-aware)
  int f_max = m >> 10; if (f_max > 599) f_max = 599;
  int f_min = (m - 3072) >> 10; if (f_min < 0) f_min = 0;
  float ws = 0.f;
  for (int f2 = f_min; f2 <= f_max; ++f2) {
    float w = winf(m - (f2 << 10));
    ws += w * w;
  }
  return (ws > 1e-11f) ? ws : 1.0f;
}

__device__ __forceinline__ float reflect_load(const float* __restrict__ x, int pos) {
  int k = pos - 2048;
  if (k < 0) k = -k;
  else if (k >= TLEN) k = 2 * TLEN - 2 - k;
  return x[k];
}

__device__ __forceinline__ float2 cmul(float2 a, float2 b) {
  return make_float2(a.x * b.x - a.y * b.y, a.x * b.y + a.y * b.x);
}
__device__ __forceinline__ float2 cadd(float2 a, float2 b) { return make_float2(a.x + b.x, a.y + b.y); }
__device__ __forceinline__ float2 csub(float2 a, float2 b) { return make_float2(a.x - b.x, a.y - b.y); }
template<int SGN>
__device__ __forceinline__ float2 muli(float2 a) {   // multiply by SGN*i
  return (SGN > 0) ? make_float2(-a.y, a.x) : make_float2(a.y, -a.x);
}

template<int SGN>
__device__ __forceinline__ void fft4(float2 v[4]) {
  float2 t0 = cadd(v[0], v[2]), t1 = csub(v[0], v[2]);
  float2 t2 = cadd(v[1], v[3]), t3 = csub(v[1], v[3]);
  float2 it3 = muli<SGN>(t3);
  v[0] = cadd(t0, t2); v[2] = csub(t0, t2);
  v[1] = cadd(t1, it3); v[3] = csub(t1, it3);
}

template<int SGN>
__device__ __forceinline__ void fft8(float2 v[8]) {
  const float C = 0.70710678118654752440f;
  const float s = (SGN > 0) ? 1.0f : -1.0f;
  float2 t0 = cadd(v[0], v[4]), t1 = csub(v[0], v[4]);
  float2 t2 = cadd(v[2], v[6]), t3 = csub(v[2], v[6]);
  float2 e0 = cadd(t0, t2), e2 = csub(t0, t2);
  float2 it3 = muli<SGN>(t3);
  float2 e1 = cadd(t1, it3), e3 = csub(t1, it3);
  t0 = cadd(v[1], v[5]); t1 = csub(v[1], v[5]);
  t2 = cadd(v[3], v[7]); t3 = csub(v[3], v[7]);
  float2 o0 = cadd(t0, t2), o2 = csub(t0, t2);
  it3 = muli<SGN>(t3);
  float2 o1 = cadd(t1, it3), o3 = csub(t1, it3);
  float2 o1w = make_float2(C * (o1.x - s * o1.y), C * (o1.y + s * o1.x));
  float2 o2w = muli<SGN>(o2);
  float2 o3w = make_float2(C * (-o3.x - s * o3.y), C * (-o3.y + s * o3.x));
  v[0] = cadd(e0, o0);  v[4] = csub(e0, o0);
  v[1] = cadd(e1, o1w); v[5] = csub(e1, o1w);
  v[2] = cadd(e2, o2w); v[6] = csub(e2, o2w);
  v[3] = cadd(e3, o3w); v[7] = csub(e3, o3w);
}

template<int SGN>
__device__ __forceinline__ void twiddle8(float2 v[8], float ang) {
  float sn, cs;
  __sincosf((SGN > 0) ? ang : -ang, &sn, &cs);
  float2 w1 = make_float2(cs, sn);
  float2 w = w1;
  v[1] = cmul(v[1], w);
#pragma unroll
  for (int r = 2; r < 8; ++r) { w = cmul(w, w1); v[r] = cmul(v[r], w); }
}

// Stockham stages 1-3 (radix-8); stage-3 result left in LDS.
template<int SGN>
__device__ __forceinline__ void fft2048_mid(float2* lds, float2 v[8], int tid) {
  fft8<SGN>(v);
#pragma unroll
  for (int r = 0; r < 8; ++r) { int i = tid * 8 + r; lds[PHYS(i)] = v[r]; }
  __syncthreads();
#pragma unroll
  for (int r = 0; r < 8; ++r) v[r] = lds[PHYS(tid + 256 * r)];
  twiddle8<SGN>(v, PI2_F * (1.0f / 64.0f) * (float)(tid & 7));      // Ns=8
  fft8<SGN>(v);
  __syncthreads();
#pragma unroll
  for (int r = 0; r < 8; ++r) { int i = ((tid >> 3) << 6) + (tid & 7) + 8 * r; lds[PHYS(i)] = v[r]; }
  __syncthreads();
#pragma unroll
  for (int r = 0; r < 8; ++r) v[r] = lds[PHYS(tid + 256 * r)];
  twiddle8<SGN>(v, PI2_F * (1.0f / 512.0f) * (float)(tid & 63));    // Ns=64
  fft8<SGN>(v);
  __syncthreads();
#pragma unroll
  for (int r = 0; r < 8; ++r) { int i = ((tid >> 6) << 9) + (tid & 63) + 64 * r; lds[PHYS(i)] = v[r]; }
  __syncthreads();
}

// final radix-4 stage (Ns=512): butterfly jj in [0,512); outputs z[jj + 512 k] = u[k]
template<int SGN>
__device__ __forceinline__ void fft2048_last(const float2* lds, int jj, float2 u[4]) {
#pragma unroll
  for (int r = 0; r < 4; ++r) u[r] = lds[PHYS(jj + 512 * r)];
  float sn, cs;
  float ang = PI2_F * (1.0f / 2048.0f) * (float)jj;
  __sincosf((SGN > 0) ? ang : -ang, &sn, &cs);
  float2 w1 = make_float2(cs, sn);
  float2 w2 = cmul(w1, w1);
  float2 w3 = cmul(w2, w1);
  u[1] = cmul(u[1], w1); u[2] = cmul(u[2], w2); u[3] = cmul(u[3], w3);
  fft4<SGN>(u);
}

// ---------------- forward STFT: one block per (n,c,f) frame ----------------
__global__ __launch_bounds__(256, 6) void stft_kernel(const float* __restrict__ audio,
                                                      float2* __restrict__ X) {
  __shared__ float2 lds[2176];
  int bid = blockIdx.x;             // nc*600 + f
  int f  = bid % NFR;
  int nc = bid / NFR;
  const float* x = audio + (size_t)nc * TLEN;
  int tid = threadIdx.x;
  int base = f * 1024;
  float2 v[8];
#pragma unroll
  for (int r = 0; r < 8; ++r) {
    int k = tid + 256 * r;
    int j0 = 2 * k;
    v[r] = make_float2(reflect_load(x, base + j0)     * winf(j0),
                       reflect_load(x, base + j0 + 1) * winf(j0 + 1));
  }
  fft2048_mid<-1>(lds, v, tid);
  fft2048_last<-1>(lds, tid,        v);
  fft2048_last<-1>(lds, tid + 256,  v + 4);
  __syncthreads();
#pragma unroll
  for (int r = 0; r < 4; ++r) lds[PHYS(tid + 512 * r)] = v[r];
#pragma unroll
  for (int r = 0; r < 4; ++r) lds[PHYS(tid + 256 + 512 * r)] = v[4 + r];
  __syncthreads();
  float2* out = X + (size_t)bid * NB;
  float sn0, cs0;
  __sincosf(-PI_F * (float)tid * (1.0f / 2048.0f), &sn0, &cs0);
  float2 ph = make_float2(cs0, sn0);
  const float2 rot = make_float2(0.92387953251128675613f, -0.38268343236508977173f);
#pragma unroll
  for (int r = 0; r < 9; ++r) {
    int k = tid + 256 * r;
    if (k <= 2048) {
      float2 Zk = lds[PHYS(k & 2047)];
      float2 Zm = lds[PHYS((2048 - k) & 2047)];
      float Ex = 0.5f * (Zk.x + Zm.x), Ey = 0.5f * (Zk.y - Zm.y);
      float Dx = 0.5f * (Zk.x - Zm.x), Dy = 0.5f * (Zk.y + Zm.y);
      float Ox = Dy, Oy = -Dx;                       // O = -i*D
      out[k] = make_float2(Ex + Ox * ph.x - Oy * ph.y, Ey + Ox * ph.y + Oy * ph.x);
    }
    ph = cmul(ph, rot);
  }
}

// ------- per-(n,chunk,b) covariance stats (float4/bin) + fused chunk max -------
__global__ __launch_bounds__(256) void stats_kernel(const float2* __restrict__ X,
                                                    float* __restrict__ stats4,
                                                    unsigned int* __restrict__ maxsq) {
  __shared__ unsigned int sm;
  if (threadIdx.x == 0) sm = 0u;
  __syncthreads();
  int b = blockIdx.x * 256 + threadIdx.x;
  bool ok = (b < NB);
  int g = blockIdx.y;                 // n*2 + chunk
  int n = g >> 1, chunk = g & 1;
  int t0 = blockIdx.z * 75;
  const float2* X0 = X + ((size_t)(n * 2 + 0) * NFR + chunk * 300 + t0) * NB + (ok ? b : 0);
  const float2* X1 = X + ((size_t)(n * 2 + 1) * NFR + chunk * 300 + t0) * NB + (ok ? b : 0);
  float s00 = 0.f, s11 = 0.f, sre = 0.f, sim = 0.f, lmax = 0.f;
  if (ok) {
    for (int t = 0; t < 75; ++t) {
      float2 a = X0[(size_t)t * NB];
      float2 c = X1[(size_t)t * NB];
      float pa = a.x * a.x + a.y * a.y;
      float pc = c.x * c.x + c.y * c.y;
      s00 += pa; s11 += pc;
      sre += a.x * c.x + a.y * c.y;
      sim += a.y * c.x - a.x * c.y;
      lmax = fmaxf(lmax, fmaxf(pa, pc));
    }
  }
  atomicMax(&sm, __float_as_uint(lmax));
  __syncthreads();
  if (threadIdx.x == 0) atomicMax(&maxsq[g], sm);
  if (ok) {
    float* sp = stats4 + ((size_t)g * NB + b) * 4;
    unsafeAtomicAdd(sp + 0, s00);
    unsafeAtomicAdd(sp + 1, s11);
    unsafeAtomicAdd(sp + 2, sre);
    unsafeAtomicAdd(sp + 3, sim);
  }
}

// ---------------- alpha_s + K = sum_s alpha per (g,b) ----------------
__global__ __launch_bounds__(256) void alpha_kernel(const float* __restrict__ Wmask,
                                                    const float4* __restrict__ stats4,
                                                    const unsigned int* __restrict__ maxsq,
                                                    float* __restrict__ alpha,
                                                    float* __restrict__ Ksum) {
  int idx = blockIdx.x * 256 + threadIdx.x;
  if (idx >= 4 * NB) return;
  int b = idx % NB;
  int g = idx / NB;
  float ma2 = fmaxf(1.0f, __uint_as_float(maxsq[g]) * 0.01f);   // max_abs^2
  float4 s4 = stats4[(size_t)g * NB + b];
  float P = 0.5f * (s4.x + s4.y) / ma2;
  float K = 0.f;
#pragma unroll
  for (int s = 0; s < 4; ++s) {
    float mv = 1.0f / (1.0f + expf(-Wmask[s * NB + b]));
    float m2 = mv * mv;
    float a = (m2 * m2) / (1e-10f + m2 * P);
    alpha[(size_t)(g * 4 + s) * NB + b] = a;
    K += a;
  }
  Ksum[(size_t)g * NB + b] = K;
}

// ------- Wiener core (s-independent field): Wc[t,c] = p̂ * (G * inv(Cxx) * x)[c] -------
__global__ __launch_bounds__(256) void wiener_kernel(const float2* __restrict__ X,
                                                     const float4* __restrict__ stats4,
                                                     const float* __restrict__ Ksum,
                                                     const unsigned int* __restrict__ maxsq,
                                                     float2* __restrict__ Wc) {
  int idx = blockIdx.x * 256 + threadIdx.x;
  if (idx >= 4 * 300 * NB) return;
  int b = idx % NB;
  int gt = idx / NB;
  int t = gt % 300;
  int g = gt / 300;
  int n = g >> 1, chunk = g & 1;
  int f = chunk * 300 + t;
  float ima2 = 1.0f / fmaxf(1.0f, __uint_as_float(maxsq[g]) * 0.01f);
  float4 s4 = stats4[(size_t)g * NB + b];
  float g00 = s4.x * ima2, g11 = s4.y * ima2, gre = s4.z * ima2, gim = s4.w * ima2;
  float K = Ksum[(size_t)g * NB + b];
  float2 x0 = X[((size_t)(n * 2 + 0) * NFR + f) * NB + b];
  float2 x1 = X[((size_t)(n * 2 + 1) * NFR + f) * NB + b];
  float ph = 0.5f * ((x0.x * x0.x + x0.y * x0.y) + (x1.x * x1.x + x1.y * x1.y)) * ima2;
  float pk = ph * K;
  float M00 = 1e-5f + pk * g00;
  float M11 = 1e-5f + pk * g11;
  float Mre = pk * gre, Mim = pk * gim;                // M01
  float det = M00 * M11 - (Mre * Mre + Mim * Mim);
  float sc = ph / det;
  float u0x = M11 * x0.x - (Mre * x1.x - Mim * x1.y);
  float u0y = M11 * x0.y - (Mre * x1.y + Mim * x1.x);
  float u1x = M00 * x1.x - (Mre * x0.x + Mim * x0.y);
  float u1y = M00 * x1.y - (Mre * x0.y - Mim * x0.x);
  float w0x = g00 * u0x + (gre * u1x - gim * u1y);
  float w0y = g00 * u0y + (gre * u1y + gim * u1x);
  float w1x = (gre * u0x + gim * u0y) + g11 * u1x;
  float w1y = (gre * u0y - gim * u0x) + g11 * u1y;
  float2* out = Wc + ((size_t)(n * NFR + f) * 2) * NB + b;
  out[0]  = make_float2(w0x * sc, w0y * sc);
  out[NB] = make_float2(w1x * sc, w1y * sc);
}

// ---- single-pass iSTFT with register OLA (8 rotating slots, all indices static) ----
// Thread t's iFFT outputs for frame f0+D sit at global accum coords
// p = 4096*j + 2t + 512*(k+2D), k=0..7. Slot q=k+2D lives in acc[q&7]; slot q is
// complete after frame D=q/2, emitted immediately, zeroed, and reused for q+8.
// All acc indices are compile-time constants (template D + unrolled k) so acc
// stays in VGPRs — round-1 regression was acc demoted to scratch (runtime index).
template<int D>
__device__ __forceinline__ void frame_accum(const float2* __restrict__ Wrow,
                                            const float* __restrict__ arow,
                                            float2* lds, int tid,
                                            float2 ph0, float2 rot,
                                            const float (&w0)[8], const float (&w1)[8],
                                            float2 (&acc)[8]) {
  float2 v[8];
  float2 ph = ph0;
#pragma unroll
  for (int r = 0; r < 8; ++r) {
    int k = tid + 256 * r;
    float akv = arow[k];
    float amv = arow[2048 - k];
    float2 sk = Wrow[k];        sk.x *= akv; sk.y *= akv;
    float2 sv = Wrow[2048 - k]; sv.x *= amv; sv.y *= amv;
    float Ex = 0.5f * (sk.x + sv.x), Ey = 0.5f * (sk.y - sv.y);
    float Dx = 0.5f * (sk.x - sv.x), Dy = 0.5f * (sk.y + sv.y);
    float Ox = Dx * ph.x - Dy * ph.y, Oy = Dx * ph.y + Dy * ph.x;  // O = D*e^{+i pi k/2048}
    v[r] = make_float2(Ex - Oy, Ey + Ox);                           // Z = E + iO
    ph = cmul(ph, rot);
  }
  fft2048_mid<1>(lds, v, tid);
#pragma unroll
  for (int half = 0; half < 2; ++half) {
    int jj = tid + 256 * half;
    float2 u[4];
    fft2048_last<1>(lds, jj, u);
#pragma unroll
    for (int r = 0; r < 4; ++r) {
      const int k = half + 2 * r;            // 0..7, compile-time
      const int slot = (k + 2 * D) & 7;      // compile-time
      acc[slot].x += u[r].x * w0[k];
      acc[slot].y += u[r].y * w1[k];
    }
  }
  __syncthreads();   // lds reused by next frame
}

// emit completed slots q=2D, 2D+1 after frame D (D=0,1,2), then zero for reuse.
template<int D>
__device__ __forceinline__ void emit_pair(int j, int base2,
                                          float* __restrict__ outp,
                                          float* __restrict__ ppart,
                                          float2 (&acc)[8]) {
  const int q0 = 2 * D, q1 = 2 * D + 1;
  if (j != 0) {
    *(float2*)&ppart[base2 + 512 * q0] = acc[q0 & 7];     // head partial, unscaled
    *(float2*)&ppart[base2 + 512 * q1] = acc[q1 & 7];
  } else if (D == 2) {
    // j=0 head complete in-block; only p in [2048,3072) maps into out
    int p0 = base2 + 512 * q0;
    int p1 = base2 + 512 * q1;
    float2 a0 = acc[q0 & 7], a1 = acc[q1 & 7];
    outp[p0 - 2048] = a0.x / wsum_at(p0);
    outp[p0 - 2047] = a0.y / wsum_at(p0 + 1);
    outp[p1 - 2048] = a1.x / wsum_at(p1);
    outp[p1 - 2047] = a1.y / wsum_at(p1 + 1);
  }                                                        // D=0,1 at j=0: p<2048, discard
  acc[q0 & 7] = make_float2(0.f, 0.f);
  acc[q1 & 7] = make_float2(0.f, 0.f);
}

__global__ __launch_bounds__(256, 4) void istft_fused_kernel(const float2* __restrict__ Wc,
                                                             const float* __restrict__ alpha,
                                                             float* __restrict__ part,
                                                             float* __restrict__ out) {
  __shared__ float2 lds[2176];
  int bid = blockIdx.x;                  // plane*150 + j
  int j = bid % 150;
  int plane = bid / 150;
  int c = plane & 1;
  int s = (plane >> 1) & 3;
  int n = plane >> 3;
  int f0 = 4 * j;
  int g = n * 2 + (j >= 75 ? 1 : 0);     // chunk boundary aligns with 4-frame groups
  int tid = threadIdx.x;
  const float* __restrict__ arow = alpha + (size_t)(g * 4 + s) * NB;
  float* __restrict__ outp = out + (size_t)plane * TLEN;
  float* __restrict__ ppart = part + ((size_t)plane * 150 + j) * 2 * 3072;

  // frame-invariant per-thread constants: window*scale and Hermitian phase
  const float scale = 1.0f / 2048.0f;
  float w0[8], w1[8];
#pragma unroll
  for (int k = 0; k < 8; ++k) {
    int j0 = 2 * tid + 512 * k;
    w0[k] = winf(j0) * scale;
    w1[k] = winf(j0 + 1) * scale;
  }
  float sn0, cs0;
  __sincosf(PI_F * (float)tid * (1.0f / 2048.0f), &sn0, &cs0);
  const float2 ph0 = make_float2(cs0, sn0);
  const float2 rot = make_float2(0.92387953251128675613f, 0.38268343236508977173f);

  float2 acc[8];
#pragma unroll
  for (int q = 0; q < 8; ++q) acc[q] = make_float2(0.f, 0.f);

  const float2* __restrict__ Wbase = Wc + ((size_t)(n * NFR + f0) * 2 + c) * NB;
  int base2 = 2 * tid;

  frame_accum<0>(Wbase + 0 * 2 * NB, arow, lds, tid, ph0, rot, w0, w1, acc);
  emit_pair<0>(j, base2, outp, ppart, acc);
  frame_accum<1>(Wbase + 1 * 2 * NB, arow, lds, tid, ph0, rot, w0, w1, acc);
  emit_pair<1>(j, base2, outp, ppart, acc);
  frame_accum<2>(Wbase + 2 * 2 * NB, arow, lds, tid, ph0, rot, w0, w1, acc);
  emit_pair<2>(j, base2, outp, ppart, acc);
  frame_accum<3>(Wbase + 3 * 2 * NB, arow, lds, tid, ph0, rot, w0, w1, acc);

  const float inv15 = 0.66666666666666667f;   // 1/wsum interior (=1.5)

  // interior q=6,7: p = 4096j + 2t + {3072,3584}; always wsum=1.5
  {
    int p = 4096 * j + base2 + 1024;          // (3072 - 2048)
    *(float2*)&outp[p]       = make_float2(acc[6].x * inv15, acc[6].y * inv15);
    *(float2*)&outp[p + 512] = make_float2(acc[7].x * inv15, acc[7].y * inv15);
  }
  if (j == 149) {
    // tail complete in-block; only p in [614400,615424) maps into out (q=8,9)
    {
      int p = 4096 * 149 + base2 + 512 * 8;
      float2 a = acc[8 & 7];
      outp[p - 2048] = a.x / wsum_at(p);
      outp[p - 2047] = a.y / wsum_at(p + 1);
    }
    {
      int p = 4096 * 149 + base2 + 512 * 9;
      float2 a = acc[9 & 7];
      outp[p - 2048] = a.x / wsum_at(p);
      outp[p - 2047] = a.y / wsum_at(p + 1);
    }
    // q=10..13 fall outside out: discard
  } else {
#pragma unroll
    for (int qq = 0; qq < 6; ++qq) {          // q = 8 + qq, slot = (8+qq)&7 = qq
      *(float2*)&ppart[3072 + base2 + 512 * qq] = acc[qq];
    }
  }
}

// ---- boundary combine: out[4096j-2048 .. +3072) = (head[j] + tail[j-1]) / 1.5 ----
__global__ __launch_bounds__(256) void combine_kernel(const float* __restrict__ part,
                                                      float* __restrict__ out) {
  int bid = blockIdx.x;            // plane*149 + (j-1)
  int jm = bid % 149;
  int plane = bid / 149;
  int j = jm + 1;
  const float4* hp = (const float4*)(part + (((size_t)plane * 150 + j) * 2 + 0) * 3072);
  const float4* tp = (const float4*)(part + (((size_t)plane * 150 + (j - 1)) * 2 + 1) * 3072);
  float4* outp = (float4*)(out + (size_t)plane * TLEN + (4096 * j - 2048));
  const float inv15 = 0.66666666666666667f;
  int t = threadIdx.x;
#pragma unroll
  for (int i = 0; i < 3; ++i) {
    int idx = t + 256 * i;         // float4 index within 768
    float4 h = hp[idx], tl = tp[idx];
    float4 o;
    o.x = (h.x + tl.x) * inv15;
    o.y = (h.y + tl.y) * inv15;
    o.z = (h.z + tl.z) * inv15;
    o.w = (h.w + tl.w) * inv15;
    outp[idx] = o;
  }
}

extern "C" void kernel_launch(void* const* d_in, const int* in_sizes, int n_in,
                              void* d_out, int out_size, void* d_ws, size_t ws_size,
                              hipStream_t stream) {
  const float* audio = (const float*)d_in[0];
  const float* Wmask = (const float*)d_in[1];
  float* out = (float*)d_out;

  // layout: [stats4 131136 | maxsq 64] (zeroed) | alpha 131,136 | Ksum 32,784 |
  //         Wc 39,340,800 | X 39,340,800 (aliased by part 58,982,400 — X is dead
  //         after wiener_kernel, partials are written only by istft_fused_kernel)
  char* ws = (char*)d_ws;
  const size_t off_stats4 = 0;
  const size_t off_maxsq  = 131136;
  const size_t zero_span  = 131200;
  const size_t off_alpha  = zero_span;                 // 131,200
  const size_t off_Ksum   = off_alpha + 131136;        // 262,336
  const size_t off_Wc     = off_Ksum + 32784;          // 295,120 (16B aligned)
  const size_t off_X      = off_Wc + 39340800;         // 39,635,920 (16B aligned)
  const size_t off_part   = off_X;                     // alias; total 98,618,320 B

  float*        stats4f = (float*)(ws + off_stats4);
  float4*       stats4  = (float4*)(ws + off_stats4);
  unsigned int* maxsq   = (unsigned int*)(ws + off_maxsq);
  float*        alpha   = (float*)(ws + off_alpha);
  float*        Ksum    = (float*)(ws + off_Ksum);
  float2*       Wc      = (float2*)(ws + off_Wc);
  float2*       X       = (float2*)(ws + off_X);
  float*        part    = (float*)(ws + off_part);

  hipMemsetAsync(ws, 0, zero_span, stream);

  stft_kernel<<<2400, 256, 0, stream>>>(audio, X);
  stats_kernel<<<dim3(9, 4, 4), 256, 0, stream>>>(X, stats4f, maxsq);
  alpha_kernel<<<(4 * NB + 255) / 256, 256, 0, stream>>>(Wmask, stats4, maxsq, alpha, Ksum);
  wiener_kernel<<<(4 * 300 * NB + 255) / 256, 256, 0, stream>>>(X, stats4, Ksum, maxsq, Wc);
  istft_fused_kernel<<<2400, 256, 0, stream>>>(Wc, alpha, part, out);
  combine_kernel<<<16 * 149, 256, 0, stream>>>(part, out);
}

// Round 3
// 372.463 us; speedup vs baseline: 1.0819x; 1.0819x over previous
//
#include <hip/hip_runtime.h>
#include <math.h>

#define TLEN 613376
#define NFR  600             // total frames
#define NB   2049            // bins
#define PI_F  3.14159265358979323846f
#define PI2_F 6.28318530717958647693f
#define PHYS(i) ((i) + ((i) >> 4))   // LDS pad

// periodic hann window
__device__ __forceinline__ float winf(int j) {
  return 0.5f - 0.5f * __cosf(1.5339807878856412e-3f * (float)j);  // 2*pi/4096
}

__device__ __forceinline__ float wsum_at(int m) {   // OLA window-power sum (edge-aware)
  int f_max = m >> 10; if (f_max > 599) f_max = 599;
  int f_min = (m - 3072) >> 10; if (f_min < 0) f_min = 0;
  float ws = 0.f;
  for (int f2 = f_min; f2 <= f_max; ++f2) {
    float w = winf(m - (f2 << 10));
    ws += w * w;
  }
  return (ws > 1e-11f) ? ws : 1.0f;
}

__device__ __forceinline__ float reflect_load(const float* __restrict__ x, int pos) {
  int k = pos - 2048;
  if (k < 0) k = -k;
  else if (k >= TLEN) k = 2 * TLEN - 2 - k;
  return x[k];
}

__device__ __forceinline__ float2 cmul(float2 a, float2 b) {
  return make_float2(a.x * b.x - a.y * b.y, a.x * b.y + a.y * b.x);
}
__device__ __forceinline__ float2 cadd(float2 a, float2 b) { return make_float2(a.x + b.x, a.y + b.y); }
__device__ __forceinline__ float2 csub(float2 a, float2 b) { return make_float2(a.x - b.x, a.y - b.y); }
template<int SGN>
__device__ __forceinline__ float2 muli(float2 a) {   // multiply by SGN*i
  return (SGN > 0) ? make_float2(-a.y, a.x) : make_float2(a.y, -a.x);
}

template<int SGN>
__device__ __forceinline__ void fft4(float2 v[4]) {
  float2 t0 = cadd(v[0], v[2]), t1 = csub(v[0], v[2]);
  float2 t2 = cadd(v[1], v[3]), t3 = csub(v[1], v[3]);
  float2 it3 = muli<SGN>(t3);
  v[0] = cadd(t0, t2); v[2] = csub(t0, t2);
  v[1] = cadd(t1, it3); v[3] = csub(t1, it3);
}

template<int SGN>
__device__ __forceinline__ void fft8(float2 v[8]) {
  const float C = 0.70710678118654752440f;
  const float s = (SGN > 0) ? 1.0f : -1.0f;
  float2 t0 = cadd(v[0], v[4]), t1 = csub(v[0], v[4]);
  float2 t2 = cadd(v[2], v[6]), t3 = csub(v[2], v[6]);
  float2 e0 = cadd(t0, t2), e2 = csub(t0, t2);
  float2 it3 = muli<SGN>(t3);
  float2 e1 = cadd(t1, it3), e3 = csub(t1, it3);
  t0 = cadd(v[1], v[5]); t1 = csub(v[1], v[5]);
  t2 = cadd(v[3], v[7]); t3 = csub(v[3], v[7]);
  float2 o0 = cadd(t0, t2), o2 = csub(t0, t2);
  it3 = muli<SGN>(t3);
  float2 o1 = cadd(t1, it3), o3 = csub(t1, it3);
  float2 o1w = make_float2(C * (o1.x - s * o1.y), C * (o1.y + s * o1.x));
  float2 o2w = muli<SGN>(o2);
  float2 o3w = make_float2(C * (-o3.x - s * o3.y), C * (-o3.y + s * o3.x));
  v[0] = cadd(e0, o0);  v[4] = csub(e0, o0);
  v[1] = cadd(e1, o1w); v[5] = csub(e1, o1w);
  v[2] = cadd(e2, o2w); v[6] = csub(e2, o2w);
  v[3] = cadd(e3, o3w); v[7] = csub(e3, o3w);
}

template<int SGN>
__device__ __forceinline__ void twiddle8(float2 v[8], float ang) {
  float sn, cs;
  __sincosf((SGN > 0) ? ang : -ang, &sn, &cs);
  float2 w1 = make_float2(cs, sn);
  float2 w = w1;
  v[1] = cmul(v[1], w);
#pragma unroll
  for (int r = 2; r < 8; ++r) { w = cmul(w, w1); v[r] = cmul(v[r], w); }
}

// Stockham stages 1-3 (radix-8); stage-3 result left in LDS.
template<int SGN>
__device__ __forceinline__ void fft2048_mid(float2* lds, float2 v[8], int tid) {
  fft8<SGN>(v);
#pragma unroll
  for (int r = 0; r < 8; ++r) { int i = tid * 8 + r; lds[PHYS(i)] = v[r]; }
  __syncthreads();
#pragma unroll
  for (int r = 0; r < 8; ++r) v[r] = lds[PHYS(tid + 256 * r)];
  twiddle8<SGN>(v, PI2_F * (1.0f / 64.0f) * (float)(tid & 7));      // Ns=8
  fft8<SGN>(v);
  __syncthreads();
#pragma unroll
  for (int r = 0; r < 8; ++r) { int i = ((tid >> 3) << 6) + (tid & 7) + 8 * r; lds[PHYS(i)] = v[r]; }
  __syncthreads();
#pragma unroll
  for (int r = 0; r < 8; ++r) v[r] = lds[PHYS(tid + 256 * r)];
  twiddle8<SGN>(v, PI2_F * (1.0f / 512.0f) * (float)(tid & 63));    // Ns=64
  fft8<SGN>(v);
  __syncthreads();
#pragma unroll
  for (int r = 0; r < 8; ++r) { int i = ((tid >> 6) << 9) + (tid & 63) + 64 * r; lds[PHYS(i)] = v[r]; }
  __syncthreads();
}

// final radix-4 stage (Ns=512): butterfly jj in [0,512); outputs z[jj + 512 k] = u[k]
template<int SGN>
__device__ __forceinline__ void fft2048_last(const float2* lds, int jj, float2 u[4]) {
#pragma unroll
  for (int r = 0; r < 4; ++r) u[r] = lds[PHYS(jj + 512 * r)];
  float sn, cs;
  float ang = PI2_F * (1.0f / 2048.0f) * (float)jj;
  __sincosf((SGN > 0) ? ang : -ang, &sn, &cs);
  float2 w1 = make_float2(cs, sn);
  float2 w2 = cmul(w1, w1);
  float2 w3 = cmul(w2, w1);
  u[1] = cmul(u[1], w1); u[2] = cmul(u[2], w2); u[3] = cmul(u[3], w3);
  fft4<SGN>(u);
}

// ---------------- forward STFT: one block per (n,c,f) frame ----------------
__global__ __launch_bounds__(256, 6) void stft_kernel(const float* __restrict__ audio,
                                                      float2* __restrict__ X) {
  __shared__ float2 lds[2176];
  int bid = blockIdx.x;             // nc*600 + f
  int f  = bid % NFR;
  int nc = bid / NFR;
  const float* x = audio + (size_t)nc * TLEN;
  int tid = threadIdx.x;
  int base = f * 1024;
  float2 v[8];
#pragma unroll
  for (int r = 0; r < 8; ++r) {
    int k = tid + 256 * r;
    int j0 = 2 * k;
    v[r] = make_float2(reflect_load(x, base + j0)     * winf(j0),
                       reflect_load(x, base + j0 + 1) * winf(j0 + 1));
  }
  fft2048_mid<-1>(lds, v, tid);
  fft2048_last<-1>(lds, tid,        v);
  fft2048_last<-1>(lds, tid + 256,  v + 4);
  __syncthreads();
#pragma unroll
  for (int r = 0; r < 4; ++r) lds[PHYS(tid + 512 * r)] = v[r];
#pragma unroll
  for (int r = 0; r < 4; ++r) lds[PHYS(tid + 256 + 512 * r)] = v[4 + r];
  __syncthreads();
  float2* out = X + (size_t)bid * NB;
  float sn0, cs0;
  __sincosf(-PI_F * (float)tid * (1.0f / 2048.0f), &sn0, &cs0);
  float2 ph = make_float2(cs0, sn0);
  const float2 rot = make_float2(0.92387953251128675613f, -0.38268343236508977173f);
#pragma unroll
  for (int r = 0; r < 9; ++r) {
    int k = tid + 256 * r;
    if (k <= 2048) {
      float2 Zk = lds[PHYS(k & 2047)];
      float2 Zm = lds[PHYS((2048 - k) & 2047)];
      float Ex = 0.5f * (Zk.x + Zm.x), Ey = 0.5f * (Zk.y - Zm.y);
      float Dx = 0.5f * (Zk.x - Zm.x), Dy = 0.5f * (Zk.y + Zm.y);
      float Ox = Dy, Oy = -Dx;                       // O = -i*D
      out[k] = make_float2(Ex + Ox * ph.x - Oy * ph.y, Ey + Ox * ph.y + Oy * ph.x);
    }
    ph = cmul(ph, rot);
  }
}

// ------- per-(n,chunk,b) covariance stats (float4/bin) + fused chunk max -------
__global__ __launch_bounds__(256) void stats_kernel(const float2* __restrict__ X,
                                                    float* __restrict__ stats4,
                                                    unsigned int* __restrict__ maxsq) {
  __shared__ unsigned int sm;
  if (threadIdx.x == 0) sm = 0u;
  __syncthreads();
  int b = blockIdx.x * 256 + threadIdx.x;
  bool ok = (b < NB);
  int g = blockIdx.y;                 // n*2 + chunk
  int n = g >> 1, chunk = g & 1;
  int t0 = blockIdx.z * 75;
  const float2* X0 = X + ((size_t)(n * 2 + 0) * NFR + chunk * 300 + t0) * NB + (ok ? b : 0);
  const float2* X1 = X + ((size_t)(n * 2 + 1) * NFR + chunk * 300 + t0) * NB + (ok ? b : 0);
  float s00 = 0.f, s11 = 0.f, sre = 0.f, sim = 0.f, lmax = 0.f;
  if (ok) {
    for (int t = 0; t < 75; ++t) {
      float2 a = X0[(size_t)t * NB];
      float2 c = X1[(size_t)t * NB];
      float pa = a.x * a.x + a.y * a.y;
      float pc = c.x * c.x + c.y * c.y;
      s00 += pa; s11 += pc;
      sre += a.x * c.x + a.y * c.y;
      sim += a.y * c.x - a.x * c.y;
      lmax = fmaxf(lmax, fmaxf(pa, pc));
    }
  }
  atomicMax(&sm, __float_as_uint(lmax));
  __syncthreads();
  if (threadIdx.x == 0) atomicMax(&maxsq[g], sm);
  if (ok) {
    float* sp = stats4 + ((size_t)g * NB + b) * 4;
    unsafeAtomicAdd(sp + 0, s00);
    unsafeAtomicAdd(sp + 1, s11);
    unsafeAtomicAdd(sp + 2, sre);
    unsafeAtomicAdd(sp + 3, sim);
  }
}

// ---------------- alpha_s + K = sum_s alpha per (g,b) ----------------
__global__ __launch_bounds__(256) void alpha_kernel(const float* __restrict__ Wmask,
                                                    const float4* __restrict__ stats4,
                                                    const unsigned int* __restrict__ maxsq,
                                                    float* __restrict__ alpha,
                                                    float* __restrict__ Ksum) {
  int idx = blockIdx.x * 256 + threadIdx.x;
  if (idx >= 4 * NB) return;
  int b = idx % NB;
  int g = idx / NB;
  float ma2 = fmaxf(1.0f, __uint_as_float(maxsq[g]) * 0.01f);   // max_abs^2
  float4 s4 = stats4[(size_t)g * NB + b];
  float P = 0.5f * (s4.x + s4.y) / ma2;
  float K = 0.f;
#pragma unroll
  for (int s = 0; s < 4; ++s) {
    float mv = 1.0f / (1.0f + expf(-Wmask[s * NB + b]));
    float m2 = mv * mv;
    float a = (m2 * m2) / (1e-10f + m2 * P);
    alpha[(size_t)(g * 4 + s) * NB + b] = a;
    K += a;
  }
  Ksum[(size_t)g * NB + b] = K;
}

// ------- Wiener core (s-independent field): Wc[t,c] = p̂ * (G * inv(Cxx) * x)[c] -------
__global__ __launch_bounds__(256) void wiener_kernel(const float2* __restrict__ X,
                                                     const float4* __restrict__ stats4,
                                                     const float* __restrict__ Ksum,
                                                     const unsigned int* __restrict__ maxsq,
                                                     float2* __restrict__ Wc) {
  int idx = blockIdx.x * 256 + threadIdx.x;
  if (idx >= 4 * 300 * NB) return;
  int b = idx % NB;
  int gt = idx / NB;
  int t = gt % 300;
  int g = gt / 300;
  int n = g >> 1, chunk = g & 1;
  int f = chunk * 300 + t;
  float ima2 = 1.0f / fmaxf(1.0f, __uint_as_float(maxsq[g]) * 0.01f);
  float4 s4 = stats4[(size_t)g * NB + b];
  float g00 = s4.x * ima2, g11 = s4.y * ima2, gre = s4.z * ima2, gim = s4.w * ima2;
  float K = Ksum[(size_t)g * NB + b];
  float2 x0 = X[((size_t)(n * 2 + 0) * NFR + f) * NB + b];
  float2 x1 = X[((size_t)(n * 2 + 1) * NFR + f) * NB + b];
  float ph = 0.5f * ((x0.x * x0.x + x0.y * x0.y) + (x1.x * x1.x + x1.y * x1.y)) * ima2;
  float pk = ph * K;
  float M00 = 1e-5f + pk * g00;
  float M11 = 1e-5f + pk * g11;
  float Mre = pk * gre, Mim = pk * gim;                // M01
  float det = M00 * M11 - (Mre * Mre + Mim * Mim);
  float sc = ph / det;
  float u0x = M11 * x0.x - (Mre * x1.x - Mim * x1.y);
  float u0y = M11 * x0.y - (Mre * x1.y + Mim * x1.x);
  float u1x = M00 * x1.x - (Mre * x0.x + Mim * x0.y);
  float u1y = M00 * x1.y - (Mre * x0.y - Mim * x0.x);
  float w0x = g00 * u0x + (gre * u1x - gim * u1y);
  float w0y = g00 * u0y + (gre * u1y + gim * u1x);
  float w1x = (gre * u0x + gim * u0y) + g11 * u1x;
  float w1y = (gre * u0y - gim * u0x) + g11 * u1y;
  float2* out = Wc + ((size_t)(n * NFR + f) * 2) * NB + b;
  out[0]  = make_float2(w0x * sc, w0y * sc);
  out[NB] = make_float2(w1x * sc, w1y * sc);
}

// ---- single-pass iSTFT: OLA state in LDS (accs[8][256]); ONE FFT body (no unroll) ----
// Thread t's iFFT outputs for frame f0+d sit at global coords
// p = 4096*j + 2t + 512*(k+2d), k=0..7. Slot q=k+2d lives in accs[(q&7)][t]; slot q
// completes after frame d=q/2, is emitted, zeroed, and reused for q+8. accs is LDS so
// runtime q indexing is legal (round-1/2 regression: register acc -> scratch spills).
// Each thread touches only accs[.][tid] -> no extra barriers, conflict-free access.
// Blocks are XCD-grouped: the 4 s-planes sharing one Wc row map to the same XCD's L2.
__global__ __launch_bounds__(256, 4) void istft_fused_kernel(const float2* __restrict__ Wc,
                                                             const float* __restrict__ alpha,
                                                             float* __restrict__ part,
                                                             float* __restrict__ out) {
  __shared__ float2 lds[2176];
  __shared__ float2 accs[2048];          // [slot 0..7][tid 0..255]
  int bid = blockIdx.x;
  // XCD-grouped decode: bid = (g2 & 7) + 8*((g2>>3)*4 + s), g2 = (n*2+c)*150 + j
  int x = bid & 7;
  int inner = bid >> 3;
  int s = inner & 3;
  int g2 = x + 8 * (inner >> 2);         // 0..599
  int j = g2 % 150;
  int nc = g2 / 150;
  int n = nc >> 1, c = nc & 1;
  int plane = n * 8 + s * 2 + c;         // out layout (N,S,C)
  int f0 = 4 * j;
  int g = n * 2 + (j >= 75 ? 1 : 0);     // chunk boundary aligns with 4-frame groups
  int tid = threadIdx.x;
  const float* __restrict__ arow = alpha + (size_t)(g * 4 + s) * NB;
  float* __restrict__ outp = out + (size_t)plane * TLEN;
  float* __restrict__ ppart = part + ((size_t)plane * 150 + j) * 2 * 3072;

  const float scale = 1.0f / 2048.0f;
  float sn0, cs0;
  __sincosf(PI_F * (float)tid * (1.0f / 2048.0f), &sn0, &cs0);
  const float2 ph0 = make_float2(cs0, sn0);
  const float2 rot = make_float2(0.92387953251128675613f, 0.38268343236508977173f);
  int base2 = 2 * tid;

#pragma unroll
  for (int q = 0; q < 8; ++q) accs[q * 256 + tid] = make_float2(0.f, 0.f);

#pragma unroll 1
  for (int d = 0; d < 4; ++d) {
    const float2* __restrict__ Wrow = Wc + ((size_t)(n * NFR + (f0 + d)) * 2 + c) * NB;
    // stage alpha*W row into lds[0..2048] (linear indices; FFT overwrites later)
#pragma unroll
    for (int r = 0; r < 8; ++r) {
      int k = tid + 256 * r;
      float a = arow[k];
      float2 w = Wrow[k];
      lds[k] = make_float2(w.x * a, w.y * a);
    }
    if (tid == 0) {
      float a = arow[2048];
      float2 w = Wrow[2048];
      lds[2048] = make_float2(w.x * a, w.y * a);
    }
    __syncthreads();
    // Hermitian pack from staged row (forward + mirrored reads now in LDS)
    float2 v[8];
    float2 ph = ph0;
#pragma unroll
    for (int r = 0; r < 8; ++r) {
      int k = tid + 256 * r;
      float2 sk = lds[k];
      float2 sv = lds[2048 - k];
      float Ex = 0.5f * (sk.x + sv.x), Ey = 0.5f * (sk.y - sv.y);
      float Dx = 0.5f * (sk.x - sv.x), Dy = 0.5f * (sk.y + sv.y);
      float Ox = Dx * ph.x - Dy * ph.y, Oy = Dx * ph.y + Dy * ph.x;  // O = D*e^{+i pi k/2048}
      v[r] = make_float2(Ex - Oy, Ey + Ox);                           // Z = E + iO
      ph = cmul(ph, rot);
    }
    __syncthreads();   // staged reads complete before FFT writes lds
    fft2048_mid<1>(lds, v, tid);
#pragma unroll
    for (int half = 0; half < 2; ++half) {
      int jj = tid + 256 * half;
      float2 u[4];
      fft2048_last<1>(lds, jj, u);
#pragma unroll
      for (int r = 0; r < 4; ++r) {
        int k = half + 2 * r;                  // 0..7 compile-time
        int slot = ((k + 2 * d) & 7) * 256 + tid;   // runtime d: LDS index, fine
        float2 a = accs[slot];
        a.x += u[r].x * (winf(base2 + 512 * k) * scale);
        a.y += u[r].y * (winf(base2 + 512 * k + 1) * scale);
        accs[slot] = a;
      }
    }
    // emit completed slots q0=2d, q1=2d+1 (d<3), zero for reuse as q+8
    if (d < 3) {
      int q0 = 2 * d;
      float2 a0 = accs[q0 * 256 + tid];
      float2 a1 = accs[(q0 + 1) * 256 + tid];
      if (j != 0) {
        *(float2*)&ppart[base2 + 512 * q0] = a0;        // head partial, unscaled
        *(float2*)&ppart[base2 + 512 * (q0 + 1)] = a1;
      } else if (d == 2) {
        // j=0 head complete in-block; only p in [2048,3072) maps into out
        int p0 = base2 + 512 * q0, p1 = p0 + 512;
        outp[p0 - 2048] = a0.x / wsum_at(p0);
        outp[p0 - 2047] = a0.y / wsum_at(p0 + 1);
        outp[p1 - 2048] = a1.x / wsum_at(p1);
        outp[p1 - 2047] = a1.y / wsum_at(p1 + 1);
      }                                                  // j=0, d=0,1: p<2048, discard
      accs[q0 * 256 + tid] = make_float2(0.f, 0.f);
      accs[(q0 + 1) * 256 + tid] = make_float2(0.f, 0.f);
    }
    __syncthreads();   // lds (FFT buffer) reused by next frame's staging
  }

  const float inv15 = 0.66666666666666667f;   // 1/wsum interior (=1.5)
  // interior q=6,7: p = 4096j + 2t + {3072,3584}; always wsum=1.5
  {
    float2 a6 = accs[6 * 256 + tid];
    float2 a7 = accs[7 * 256 + tid];
    int p = 4096 * j + base2 + 1024;          // (3072 - 2048)
    *(float2*)&outp[p]       = make_float2(a6.x * inv15, a6.y * inv15);
    *(float2*)&outp[p + 512] = make_float2(a7.x * inv15, a7.y * inv15);
  }
  if (j == 149) {
    // tail complete in-block; only p in [614400,615424) maps into out (q=8,9)
#pragma unroll
    for (int q = 8; q <= 9; ++q) {
      int p = 4096 * 149 + base2 + 512 * q;
      float2 a = accs[(q & 7) * 256 + tid];
      outp[p - 2048] = a.x / wsum_at(p);
      outp[p - 2047] = a.y / wsum_at(p + 1);
    }
    // q=10..13 fall outside out: discard
  } else {
#pragma unroll
    for (int qq = 0; qq < 6; ++qq) {          // q = 8+qq lives in slot qq
      float2 a = accs[qq * 256 + tid];
      *(float2*)&ppart[3072 + base2 + 512 * qq] = a;    // tail partial, unscaled
    }
  }
}

// ---- boundary combine: out[4096j-2048 .. +3072) = (head[j] + tail[j-1]) / 1.5 ----
__global__ __launch_bounds__(256) void combine_kernel(const float* __restrict__ part,
                                                      float* __restrict__ out) {
  int bid = blockIdx.x;            // plane*149 + (j-1)
  int jm = bid % 149;
  int plane = bid / 149;
  int j = jm + 1;
  const float4* hp = (const float4*)(part + (((size_t)plane * 150 + j) * 2 + 0) * 3072);
  const float4* tp = (const float4*)(part + (((size_t)plane * 150 + (j - 1)) * 2 + 1) * 3072);
  float4* outp = (float4*)(out + (size_t)plane * TLEN + (4096 * j - 2048));
  const float inv15 = 0.66666666666666667f;
  int t = threadIdx.x;
#pragma unroll
  for (int i = 0; i < 3; ++i) {
    int idx = t + 256 * i;         // float4 index within 768
    float4 h = hp[idx], tl = tp[idx];
    float4 o;
    o.x = (h.x + tl.x) * inv15;
    o.y = (h.y + tl.y) * inv15;
    o.z = (h.z + tl.z) * inv15;
    o.w = (h.w + tl.w) * inv15;
    outp[idx] = o;
  }
}

extern "C" void kernel_launch(void* const* d_in, const int* in_sizes, int n_in,
                              void* d_out, int out_size, void* d_ws, size_t ws_size,
                              hipStream_t stream) {
  const float* audio = (const float*)d_in[0];
  const float* Wmask = (const float*)d_in[1];
  float* out = (float*)d_out;

  // layout: [stats4 131136 | maxsq 64] (zeroed) | alpha 131,136 | Ksum 32,784 |
  //         Wc 39,340,800 | X 39,340,800 (aliased by part 58,982,400 — X is dead
  //         after wiener_kernel, partials are written only by istft_fused_kernel)
  char* ws = (char*)d_ws;
  const size_t off_stats4 = 0;
  const size_t off_maxsq  = 131136;
  const size_t zero_span  = 131200;
  const size_t off_alpha  = zero_span;                 // 131,200
  const size_t off_Ksum   = off_alpha + 131136;        // 262,336
  const size_t off_Wc     = off_Ksum + 32784;          // 295,120 (16B aligned)
  const size_t off_X      = off_Wc + 39340800;         // 39,635,920 (16B aligned)
  const size_t off_part   = off_X;                     // alias; total 98,618,320 B

  float*        stats4f = (float*)(ws + off_stats4);
  float4*       stats4  = (float4*)(ws + off_stats4);
  unsigned int* maxsq   = (unsigned int*)(ws + off_maxsq);
  float*        alpha   = (float*)(ws + off_alpha);
  float*        Ksum    = (float*)(ws + off_Ksum);
  float2*       Wc      = (float2*)(ws + off_Wc);
  float2*       X       = (float2*)(ws + off_X);
  float*        part    = (float*)(ws + off_part);

  hipMemsetAsync(ws, 0, zero_span, stream);

  stft_kernel<<<2400, 256, 0, stream>>>(audio, X);
  stats_kernel<<<dim3(9, 4, 4), 256, 0, stream>>>(X, stats4f, maxsq);
  alpha_kernel<<<(4 * NB + 255) / 256, 256, 0, stream>>>(Wmask, stats4, maxsq, alpha, Ksum);
  wiener_kernel<<<(4 * 300 * NB + 255) / 256, 256, 0, stream>>>(X, stats4, Ksum, maxsq, Wc);
  istft_fused_kernel<<<2400, 256, 0, stream>>>(Wc, alpha, part, out);
  combine_kernel<<<16 * 149, 256, 0, stream>>>(part, out);
}

// Round 4
// 232.435 us; speedup vs baseline: 1.7337x; 1.6024x over previous
//
#include <hip/hip_runtime.h>
#include <math.h>

#define TLEN 613376
#define OLEN 617472          // 4096 + 1024*599
#define NFR  600             // total frames
#define NB   2049            // bins
#define PI_F  3.14159265358979323846f
#define PI2_F 6.28318530717958647693f
#define PHYS(i) ((i) + ((i) >> 4))   // LDS pad

// periodic hann window
__device__ __forceinline__ float winf(int j) {
  return 0.5f - 0.5f * __cosf(1.5339807878856412e-3f * (float)j);  // 2*pi/4096
}

__device__ __forceinline__ float wsum_at(int m) {   // OLA window-power sum (edge-aware)
  int f_max = m >> 10; if (f_max > 599) f_max = 599;
  int f_min = (m - 3072) >> 10; if (f_min < 0) f_min = 0;
  float ws = 0.f;
  for (int f2 = f_min; f2 <= f_max; ++f2) {
    float w = winf(m - (f2 << 10));
    ws += w * w;
  }
  return (ws > 1e-11f) ? ws : 1.0f;
}

__device__ __forceinline__ float reflect_load(const float* __restrict__ x, int pos) {
  int k = pos - 2048;
  if (k < 0) k = -k;
  else if (k >= TLEN) k = 2 * TLEN - 2 - k;
  return x[k];
}

__device__ __forceinline__ float2 cmul(float2 a, float2 b) {
  return make_float2(a.x * b.x - a.y * b.y, a.x * b.y + a.y * b.x);
}
__device__ __forceinline__ float2 cadd(float2 a, float2 b) { return make_float2(a.x + b.x, a.y + b.y); }
__device__ __forceinline__ float2 csub(float2 a, float2 b) { return make_float2(a.x - b.x, a.y - b.y); }
template<int SGN>
__device__ __forceinline__ float2 muli(float2 a) {   // multiply by SGN*i
  return (SGN > 0) ? make_float2(-a.y, a.x) : make_float2(a.y, -a.x);
}

template<int SGN>
__device__ __forceinline__ void fft4(float2 v[4]) {
  float2 t0 = cadd(v[0], v[2]), t1 = csub(v[0], v[2]);
  float2 t2 = cadd(v[1], v[3]), t3 = csub(v[1], v[3]);
  float2 it3 = muli<SGN>(t3);
  v[0] = cadd(t0, t2); v[2] = csub(t0, t2);
  v[1] = cadd(t1, it3); v[3] = csub(t1, it3);
}

template<int SGN>
__device__ __forceinline__ void fft8(float2 v[8]) {
  const float C = 0.70710678118654752440f;
  const float s = (SGN > 0) ? 1.0f : -1.0f;
  float2 t0 = cadd(v[0], v[4]), t1 = csub(v[0], v[4]);
  float2 t2 = cadd(v[2], v[6]), t3 = csub(v[2], v[6]);
  float2 e0 = cadd(t0, t2), e2 = csub(t0, t2);
  float2 it3 = muli<SGN>(t3);
  float2 e1 = cadd(t1, it3), e3 = csub(t1, it3);
  t0 = cadd(v[1], v[5]); t1 = csub(v[1], v[5]);
  t2 = cadd(v[3], v[7]); t3 = csub(v[3], v[7]);
  float2 o0 = cadd(t0, t2), o2 = csub(t0, t2);
  it3 = muli<SGN>(t3);
  float2 o1 = cadd(t1, it3), o3 = csub(t1, it3);
  float2 o1w = make_float2(C * (o1.x - s * o1.y), C * (o1.y + s * o1.x));
  float2 o2w = muli<SGN>(o2);
  float2 o3w = make_float2(C * (-o3.x - s * o3.y), C * (-o3.y + s * o3.x));
  v[0] = cadd(e0, o0);  v[4] = csub(e0, o0);
  v[1] = cadd(e1, o1w); v[5] = csub(e1, o1w);
  v[2] = cadd(e2, o2w); v[6] = csub(e2, o2w);
  v[3] = cadd(e3, o3w); v[7] = csub(e3, o3w);
}

template<int SGN>
__device__ __forceinline__ void twiddle8(float2 v[8], float ang) {
  float sn, cs;
  __sincosf((SGN > 0) ? ang : -ang, &sn, &cs);
  float2 w1 = make_float2(cs, sn);
  float2 w = w1;
  v[1] = cmul(v[1], w);
#pragma unroll
  for (int r = 2; r < 8; ++r) { w = cmul(w, w1); v[r] = cmul(v[r], w); }
}

// Stockham stages 1-3 (radix-8); stage-3 result left in LDS.
template<int SGN>
__device__ __forceinline__ void fft2048_mid(float2* lds, float2 v[8], int tid) {
  fft8<SGN>(v);
#pragma unroll
  for (int r = 0; r < 8; ++r) { int i = tid * 8 + r; lds[PHYS(i)] = v[r]; }
  __syncthreads();
#pragma unroll
  for (int r = 0; r < 8; ++r) v[r] = lds[PHYS(tid + 256 * r)];
  twiddle8<SGN>(v, PI2_F * (1.0f / 64.0f) * (float)(tid & 7));      // Ns=8
  fft8<SGN>(v);
  __syncthreads();
#pragma unroll
  for (int r = 0; r < 8; ++r) { int i = ((tid >> 3) << 6) + (tid & 7) + 8 * r; lds[PHYS(i)] = v[r]; }
  __syncthreads();
#pragma unroll
  for (int r = 0; r < 8; ++r) v[r] = lds[PHYS(tid + 256 * r)];
  twiddle8<SGN>(v, PI2_F * (1.0f / 512.0f) * (float)(tid & 63));    // Ns=64
  fft8<SGN>(v);
  __syncthreads();
#pragma unroll
  for (int r = 0; r < 8; ++r) { int i = ((tid >> 6) << 9) + (tid & 63) + 64 * r; lds[PHYS(i)] = v[r]; }
  __syncthreads();
}

// final radix-4 stage (Ns=512): butterfly jj in [0,512); outputs z[jj + 512 k] = u[k]
template<int SGN>
__device__ __forceinline__ void fft2048_last(const float2* lds, int jj, float2 u[4]) {
#pragma unroll
  for (int r = 0; r < 4; ++r) u[r] = lds[PHYS(jj + 512 * r)];
  float sn, cs;
  float ang = PI2_F * (1.0f / 2048.0f) * (float)jj;
  __sincosf((SGN > 0) ? ang : -ang, &sn, &cs);
  float2 w1 = make_float2(cs, sn);
  float2 w2 = cmul(w1, w1);
  float2 w3 = cmul(w2, w1);
  u[1] = cmul(u[1], w1); u[2] = cmul(u[2], w2); u[3] = cmul(u[3], w3);
  fft4<SGN>(u);
}

// ---------------- forward STFT: one block per (n,c,f) frame ----------------
__global__ __launch_bounds__(256, 6) void stft_kernel(const float* __restrict__ audio,
                                                      float2* __restrict__ X) {
  __shared__ float2 lds[2176];
  int bid = blockIdx.x;             // nc*600 + f
  int f  = bid % NFR;
  int nc = bid / NFR;
  const float* x = audio + (size_t)nc * TLEN;
  int tid = threadIdx.x;
  int base = f * 1024;
  float2 v[8];
#pragma unroll
  for (int r = 0; r < 8; ++r) {
    int k = tid + 256 * r;
    int j0 = 2 * k;
    v[r] = make_float2(reflect_load(x, base + j0)     * winf(j0),
                       reflect_load(x, base + j0 + 1) * winf(j0 + 1));
  }
  fft2048_mid<-1>(lds, v, tid);
  fft2048_last<-1>(lds, tid,        v);
  fft2048_last<-1>(lds, tid + 256,  v + 4);
  __syncthreads();
#pragma unroll
  for (int r = 0; r < 4; ++r) lds[PHYS(tid + 512 * r)] = v[r];
#pragma unroll
  for (int r = 0; r < 4; ++r) lds[PHYS(tid + 256 + 512 * r)] = v[4 + r];
  __syncthreads();
  float2* out = X + (size_t)bid * NB;
  float sn0, cs0;
  __sincosf(-PI_F * (float)tid * (1.0f / 2048.0f), &sn0, &cs0);
  float2 ph = make_float2(cs0, sn0);
  const float2 rot = make_float2(0.92387953251128675613f, -0.38268343236508977173f);
#pragma unroll
  for (int r = 0; r < 9; ++r) {
    int k = tid + 256 * r;
    if (k <= 2048) {
      float2 Zk = lds[PHYS(k & 2047)];
      float2 Zm = lds[PHYS((2048 - k) & 2047)];
      float Ex = 0.5f * (Zk.x + Zm.x), Ey = 0.5f * (Zk.y - Zm.y);
      float Dx = 0.5f * (Zk.x - Zm.x), Dy = 0.5f * (Zk.y + Zm.y);
      float Ox = Dy, Oy = -Dx;                       // O = -i*D
      out[k] = make_float2(Ex + Ox * ph.x - Oy * ph.y, Ey + Ox * ph.y + Oy * ph.x);
    }
    ph = cmul(ph, rot);
  }
}

// ------- per-(n,chunk,b) covariance stats (float4/bin) + fused chunk max -------
__global__ __launch_bounds__(256) void stats_kernel(const float2* __restrict__ X,
                                                    float* __restrict__ stats4,
                                                    unsigned int* __restrict__ maxsq) {
  __shared__ unsigned int sm;
  if (threadIdx.x == 0) sm = 0u;
  __syncthreads();
  int b = blockIdx.x * 256 + threadIdx.x;
  bool ok = (b < NB);
  int g = blockIdx.y;                 // n*2 + chunk
  int n = g >> 1, chunk = g & 1;
  int t0 = blockIdx.z * 75;
  const float2* X0 = X + ((size_t)(n * 2 + 0) * NFR + chunk * 300 + t0) * NB + (ok ? b : 0);
  const float2* X1 = X + ((size_t)(n * 2 + 1) * NFR + chunk * 300 + t0) * NB + (ok ? b : 0);
  float s00 = 0.f, s11 = 0.f, sre = 0.f, sim = 0.f, lmax = 0.f;
  if (ok) {
    for (int t = 0; t < 75; ++t) {
      float2 a = X0[(size_t)t * NB];
      float2 c = X1[(size_t)t * NB];
      float pa = a.x * a.x + a.y * a.y;
      float pc = c.x * c.x + c.y * c.y;
      s00 += pa; s11 += pc;
      sre += a.x * c.x + a.y * c.y;
      sim += a.y * c.x - a.x * c.y;
      lmax = fmaxf(lmax, fmaxf(pa, pc));
    }
  }
  atomicMax(&sm, __float_as_uint(lmax));
  __syncthreads();
  if (threadIdx.x == 0) atomicMax(&maxsq[g], sm);
  if (ok) {
    float* sp = stats4 + ((size_t)g * NB + b) * 4;
    unsafeAtomicAdd(sp + 0, s00);
    unsafeAtomicAdd(sp + 1, s11);
    unsafeAtomicAdd(sp + 2, sre);
    unsafeAtomicAdd(sp + 3, sim);
  }
}

// ---------------- alpha_s + K = sum_s alpha per (g,b) ----------------
__global__ __launch_bounds__(256) void alpha_kernel(const float* __restrict__ Wmask,
                                                    const float4* __restrict__ stats4,
                                                    const unsigned int* __restrict__ maxsq,
                                                    float* __restrict__ alpha,
                                                    float* __restrict__ Ksum) {
  int idx = blockIdx.x * 256 + threadIdx.x;
  if (idx >= 4 * NB) return;
  int b = idx % NB;
  int g = idx / NB;
  float ma2 = fmaxf(1.0f, __uint_as_float(maxsq[g]) * 0.01f);   // max_abs^2
  float4 s4 = stats4[(size_t)g * NB + b];
  float P = 0.5f * (s4.x + s4.y) / ma2;
  float K = 0.f;
#pragma unroll
  for (int s = 0; s < 4; ++s) {
    float mv = 1.0f / (1.0f + expf(-Wmask[s * NB + b]));
    float m2 = mv * mv;
    float a = (m2 * m2) / (1e-10f + m2 * P);
    alpha[(size_t)(g * 4 + s) * NB + b] = a;
    K += a;
  }
  Ksum[(size_t)g * NB + b] = K;
}

// ------- Wiener core (s-independent field): Wc[t,c] = p̂ * (G * inv(Cxx) * x)[c] -------
__global__ __launch_bounds__(256) void wiener_kernel(const float2* __restrict__ X,
                                                     const float4* __restrict__ stats4,
                                                     const float* __restrict__ Ksum,
                                                     const unsigned int* __restrict__ maxsq,
                                                     float2* __restrict__ Wc) {
  int idx = blockIdx.x * 256 + threadIdx.x;
  if (idx >= 4 * 300 * NB) return;
  int b = idx % NB;
  int gt = idx / NB;
  int t = gt % 300;
  int g = gt / 300;
  int n = g >> 1, chunk = g & 1;
  int f = chunk * 300 + t;
  float ima2 = 1.0f / fmaxf(1.0f, __uint_as_float(maxsq[g]) * 0.01f);
  float4 s4 = stats4[(size_t)g * NB + b];
  float g00 = s4.x * ima2, g11 = s4.y * ima2, gre = s4.z * ima2, gim = s4.w * ima2;
  float K = Ksum[(size_t)g * NB + b];
  float2 x0 = X[((size_t)(n * 2 + 0) * NFR + f) * NB + b];
  float2 x1 = X[((size_t)(n * 2 + 1) * NFR + f) * NB + b];
  float ph = 0.5f * ((x0.x * x0.x + x0.y * x0.y) + (x1.x * x1.x + x1.y * x1.y)) * ima2;
  float pk = ph * K;
  float M00 = 1e-5f + pk * g00;
  float M11 = 1e-5f + pk * g11;
  float Mre = pk * gre, Mim = pk * gim;                // M01
  float det = M00 * M11 - (Mre * Mre + Mim * Mim);
  float sc = ph / det;
  float u0x = M11 * x0.x - (Mre * x1.x - Mim * x1.y);
  float u0y = M11 * x0.y - (Mre * x1.y + Mim * x1.x);
  float u1x = M00 * x1.x - (Mre * x0.x + Mim * x0.y);
  float u1y = M00 * x1.y - (Mre * x0.y - Mim * x0.x);
  float w0x = g00 * u0x + (gre * u1x - gim * u1y);
  float w0y = g00 * u0y + (gre * u1y + gim * u1x);
  float w1x = (gre * u0x + gim * u0y) + g11 * u1x;
  float w1y = (gre * u0y - gim * u0x) + g11 * u1y;
  float2* out = Wc + ((size_t)(n * NFR + f) * 2) * NB + b;
  out[0]  = make_float2(w0x * sc, w0y * sc);
  out[NB] = make_float2(w1x * sc, w1y * sc);
}

// ---- inverse rFFT per frame + NON-ATOMIC OLA; MODE: 0=store, 1=add, 2=add+finalize ----
// Round-0 structure (proven 204.6 us) with ONE change: the alpha*W row is staged in
// the FFT LDS buffer (linear idx 0..2048; physical 2176 slots >= 2049) so the
// Hermitian-mirror reads come from LDS instead of a second reversed global read.
// Saves 24.6 KB global fetch per block; numerics bit-identical (same products).
template<int MODE>
__global__ __launch_bounds__(256, 6) void istft_pass_kernel(const float2* __restrict__ Wc,
                                                            const float* __restrict__ alpha,
                                                            float* __restrict__ accum,
                                                            float* __restrict__ out,
                                                            int pass) {
  __shared__ float2 lds[2176];
  int bid = blockIdx.x;                  // plane*150 + fi, plane = ((n*4+s)*2+c)
  int fi = bid % 150;
  int plane = bid / 150;
  int c = plane & 1;
  int s = (plane >> 1) & 3;
  int n = plane >> 3;
  int f = 4 * fi + pass;
  int g = n * 2 + (f >= 300 ? 1 : 0);
  int tid = threadIdx.x;
  const float2* Wrow = Wc + ((size_t)(n * NFR + f) * 2 + c) * NB;
  const float*  arow = alpha + (size_t)(g * 4 + s) * NB;
  float* acc = accum + (size_t)plane * OLEN + (size_t)f * 1024;

  // Prefetch the OLA read-modify-write inputs before the FFT (addresses known
  // at entry) so the global read latency hides behind the FFT compute.
  // NOTE: needs the 6-wave launch bound; an 8-wave bound caps VGPRs at 64 and
  // forces scratch spills (round-6 regression).
  float2 pre[8];
  if (MODE >= 1) {
#pragma unroll
    for (int half = 0; half < 2; ++half) {
#pragma unroll
      for (int r = 0; r < 4; ++r) {
        int m = tid + 256 * half + 512 * r;
        pre[half * 4 + r] = *(const float2*)&acc[2 * m];
      }
    }
  }

  // stage alpha*W row into lds[0..2048] (linear indices; FFT overwrites later)
#pragma unroll
  for (int r = 0; r < 8; ++r) {
    int k = tid + 256 * r;
    float a = arow[k];
    float2 w = Wrow[k];
    lds[k] = make_float2(w.x * a, w.y * a);
  }
  if (tid == 0) {
    float a = arow[2048];
    float2 w = Wrow[2048];
    lds[2048] = make_float2(w.x * a, w.y * a);
  }
  __syncthreads();

  float2 v[8];
  float sn0, cs0;
  __sincosf(PI_F * (float)tid * (1.0f / 2048.0f), &sn0, &cs0);
  float2 ph = make_float2(cs0, sn0);
  const float2 rot = make_float2(0.92387953251128675613f, 0.38268343236508977173f);
#pragma unroll
  for (int r = 0; r < 8; ++r) {
    int k = tid + 256 * r;
    float2 sk = lds[k];
    float2 sv = lds[2048 - k];
    float Ex = 0.5f * (sk.x + sv.x), Ey = 0.5f * (sk.y - sv.y);
    float Dx = 0.5f * (sk.x - sv.x), Dy = 0.5f * (sk.y + sv.y);
    float Ox = Dx * ph.x - Dy * ph.y, Oy = Dx * ph.y + Dy * ph.x;  // O = D*e^{+i pi k/2048}
    v[r] = make_float2(Ex - Oy, Ey + Ox);                           // Z = E + iO
    ph = cmul(ph, rot);
  }
  __syncthreads();   // staged reads complete before FFT overwrites lds
  fft2048_mid<1>(lds, v, tid);
  float* outp = out + (size_t)plane * TLEN;
  const float scale = 1.0f / 2048.0f;
#pragma unroll
  for (int half = 0; half < 2; ++half) {
    int jj = tid + 256 * half;
    float2 u[4];
    fft2048_last<1>(lds, jj, u);
#pragma unroll
    for (int r = 0; r < 4; ++r) {
      int m = jj + 512 * r;
      int j0 = 2 * m;
      float2 val = make_float2(u[r].x * scale * winf(j0),
                               u[r].y * scale * winf(j0 + 1));
      float2* p = (float2*)&acc[j0];
      if (MODE == 0) {
        *p = val;
      } else if (MODE == 1) {
        float2 o = pre[half * 4 + r];
        val.x += o.x; val.y += o.y;
        *p = val;
      } else {
        int gm = f * 1024 + j0;                       // accum coordinate (even)
        if (gm < 615424) {                            // out covers [2048, 615424)
          float2 o = pre[half * 4 + r];
          val.x += o.x; val.y += o.y;
          float i0, i1;
          if (gm >= 3072 && gm + 1 < 614400) {        // interior: wsum == 1.5
            i0 = 0.66666666666666667f; i1 = i0;
          } else {
            i0 = 1.0f / wsum_at(gm); i1 = 1.0f / wsum_at(gm + 1);
          }
          float2* po = (float2*)&outp[gm - 2048];
          *po = make_float2(val.x * i0, val.y * i1);
        }
      }
    }
  }
  if (MODE == 0 && fi == 149) {
    // zero the plane tail [614400, OLEN) not covered by class-0 frames
    float* tail = accum + (size_t)plane * OLEN + 614400;
    for (int i = tid; i < OLEN - 614400; i += 256) tail[i] = 0.f;
  }
  if (MODE == 2 && fi == 0) {
    // finalize head samples m in [2048, 3072): complete after pass 2
    float* accp = accum + (size_t)plane * OLEN;
    for (int m = 2048 + tid; m < 3072; m += 256) {
      outp[m - 2048] = accp[m] / wsum_at(m);
    }
  }
}

extern "C" void kernel_launch(void* const* d_in, const int* in_sizes, int n_in,
                              void* d_out, int out_size, void* d_ws, size_t ws_size,
                              hipStream_t stream) {
  const float* audio = (const float*)d_in[0];
  const float* Wmask = (const float*)d_in[1];
  float* out = (float*)d_out;

  // layout: [stats4 131136 | maxsq 64] (zeroed) | X 39,340,800 | Wc 39,340,800 |
  //         accum 39,518,208 | alpha 131,136 | Ksum 32,784
  char* ws = (char*)d_ws;
  const size_t off_stats4 = 0;
  const size_t off_maxsq  = 131136;
  const size_t zero_span  = 131200;
  const size_t off_X      = zero_span;
  const size_t off_Wc     = off_X + 39340800;
  const size_t off_accum  = off_Wc + 39340800;
  const size_t off_alpha  = off_accum + 39518208;
  const size_t off_Ksum   = off_alpha + 131136;

  float*        stats4f = (float*)(ws + off_stats4);
  float4*       stats4  = (float4*)(ws + off_stats4);
  unsigned int* maxsq   = (unsigned int*)(ws + off_maxsq);
  float2*       X       = (float2*)(ws + off_X);
  float2*       Wc      = (float2*)(ws + off_Wc);
  float*        accum   = (float*)(ws + off_accum);
  float*        alpha   = (float*)(ws + off_alpha);
  float*        Ksum    = (float*)(ws + off_Ksum);

  hipMemsetAsync(ws, 0, zero_span, stream);

  stft_kernel<<<2400, 256, 0, stream>>>(audio, X);
  stats_kernel<<<dim3(9, 4, 4), 256, 0, stream>>>(X, stats4f, maxsq);
  alpha_kernel<<<(4 * NB + 255) / 256, 256, 0, stream>>>(Wmask, stats4, maxsq, alpha, Ksum);
  wiener_kernel<<<(4 * 300 * NB + 255) / 256, 256, 0, stream>>>(X, stats4, Ksum, maxsq, Wc);
  istft_pass_kernel<0><<<2400, 256, 0, stream>>>(Wc, alpha, accum, out, 0);
  istft_pass_kernel<1><<<2400, 256, 0, stream>>>(Wc, alpha, accum, out, 1);
  istft_pass_kernel<1><<<2400, 256, 0, stream>>>(Wc, alpha, accum, out, 2);
  istft_pass_kernel<2><<<2400, 256, 0, stream>>>(Wc, alpha, accum, out, 3);
}

// Round 5
// 198.340 us; speedup vs baseline: 2.0317x; 1.1719x over previous
//
#include <hip/hip_runtime.h>
#include <math.h>

#define TLEN 613376
#define OLEN 617472          // 4096 + 1024*599
#define NFR  600             // total frames
#define NB   2049            // bins
#define PI_F  3.14159265358979323846f
#define PI2_F 6.28318530717958647693f
#define PHYS(i) ((i) + ((i) >> 4))   // LDS pad

// periodic hann window
__device__ __forceinline__ float winf(int j) {
  return 0.5f - 0.5f * __cosf(1.5339807878856412e-3f * (float)j);  // 2*pi/4096
}

__device__ __forceinline__ float wsum_at(int m) {   // OLA window-power sum (edge-aware)
  int f_max = m >> 10; if (f_max > 599) f_max = 599;
  int f_min = (m - 3072) >> 10; if (f_min < 0) f_min = 0;
  float ws = 0.f;
  for (int f2 = f_min; f2 <= f_max; ++f2) {
    float w = winf(m - (f2 << 10));
    ws += w * w;
  }
  return (ws > 1e-11f) ? ws : 1.0f;
}

__device__ __forceinline__ float reflect_load(const float* __restrict__ x, int pos) {
  int k = pos - 2048;
  if (k < 0) k = -k;
  else if (k >= TLEN) k = 2 * TLEN - 2 - k;
  return x[k];
}

__device__ __forceinline__ float2 cmul(float2 a, float2 b) {
  return make_float2(a.x * b.x - a.y * b.y, a.x * b.y + a.y * b.x);
}
__device__ __forceinline__ float2 cadd(float2 a, float2 b) { return make_float2(a.x + b.x, a.y + b.y); }
__device__ __forceinline__ float2 csub(float2 a, float2 b) { return make_float2(a.x - b.x, a.y - b.y); }
template<int SGN>
__device__ __forceinline__ float2 muli(float2 a) {   // multiply by SGN*i
  return (SGN > 0) ? make_float2(-a.y, a.x) : make_float2(a.y, -a.x);
}

template<int SGN>
__device__ __forceinline__ void fft4(float2 v[4]) {
  float2 t0 = cadd(v[0], v[2]), t1 = csub(v[0], v[2]);
  float2 t2 = cadd(v[1], v[3]), t3 = csub(v[1], v[3]);
  float2 it3 = muli<SGN>(t3);
  v[0] = cadd(t0, t2); v[2] = csub(t0, t2);
  v[1] = cadd(t1, it3); v[3] = csub(t1, it3);
}

template<int SGN>
__device__ __forceinline__ void fft8(float2 v[8]) {
  const float C = 0.70710678118654752440f;
  const float s = (SGN > 0) ? 1.0f : -1.0f;
  float2 t0 = cadd(v[0], v[4]), t1 = csub(v[0], v[4]);
  float2 t2 = cadd(v[2], v[6]), t3 = csub(v[2], v[6]);
  float2 e0 = cadd(t0, t2), e2 = csub(t0, t2);
  float2 it3 = muli<SGN>(t3);
  float2 e1 = cadd(t1, it3), e3 = csub(t1, it3);
  t0 = cadd(v[1], v[5]); t1 = csub(v[1], v[5]);
  t2 = cadd(v[3], v[7]); t3 = csub(v[3], v[7]);
  float2 o0 = cadd(t0, t2), o2 = csub(t0, t2);
  it3 = muli<SGN>(t3);
  float2 o1 = cadd(t1, it3), o3 = csub(t1, it3);
  float2 o1w = make_float2(C * (o1.x - s * o1.y), C * (o1.y + s * o1.x));
  float2 o2w = muli<SGN>(o2);
  float2 o3w = make_float2(C * (-o3.x - s * o3.y), C * (-o3.y + s * o3.x));
  v[0] = cadd(e0, o0);  v[4] = csub(e0, o0);
  v[1] = cadd(e1, o1w); v[5] = csub(e1, o1w);
  v[2] = cadd(e2, o2w); v[6] = csub(e2, o2w);
  v[3] = cadd(e3, o3w); v[7] = csub(e3, o3w);
}

template<int SGN>
__device__ __forceinline__ void twiddle8(float2 v[8], float ang) {
  float sn, cs;
  __sincosf((SGN > 0) ? ang : -ang, &sn, &cs);
  float2 w1 = make_float2(cs, sn);
  float2 w = w1;
  v[1] = cmul(v[1], w);
#pragma unroll
  for (int r = 2; r < 8; ++r) { w = cmul(w, w1); v[r] = cmul(v[r], w); }
}

// Stockham stages 1-3 (radix-8); stage-3 result left in LDS.
template<int SGN>
__device__ __forceinline__ void fft2048_mid(float2* lds, float2 v[8], int tid) {
  fft8<SGN>(v);
#pragma unroll
  for (int r = 0; r < 8; ++r) { int i = tid * 8 + r; lds[PHYS(i)] = v[r]; }
  __syncthreads();
#pragma unroll
  for (int r = 0; r < 8; ++r) v[r] = lds[PHYS(tid + 256 * r)];
  twiddle8<SGN>(v, PI2_F * (1.0f / 64.0f) * (float)(tid & 7));      // Ns=8
  fft8<SGN>(v);
  __syncthreads();
#pragma unroll
  for (int r = 0; r < 8; ++r) { int i = ((tid >> 3) << 6) + (tid & 7) + 8 * r; lds[PHYS(i)] = v[r]; }
  __syncthreads();
#pragma unroll
  for (int r = 0; r < 8; ++r) v[r] = lds[PHYS(tid + 256 * r)];
  twiddle8<SGN>(v, PI2_F * (1.0f / 512.0f) * (float)(tid & 63));    // Ns=64
  fft8<SGN>(v);
  __syncthreads();
#pragma unroll
  for (int r = 0; r < 8; ++r) { int i = ((tid >> 6) << 9) + (tid & 63) + 64 * r; lds[PHYS(i)] = v[r]; }
  __syncthreads();
}

// final radix-4 stage (Ns=512): butterfly jj in [0,512); outputs z[jj + 512 k] = u[k]
template<int SGN>
__device__ __forceinline__ void fft2048_last(const float2* lds, int jj, float2 u[4]) {
#pragma unroll
  for (int r = 0; r < 4; ++r) u[r] = lds[PHYS(jj + 512 * r)];
  float sn, cs;
  float ang = PI2_F * (1.0f / 2048.0f) * (float)jj;
  __sincosf((SGN > 0) ? ang : -ang, &sn, &cs);
  float2 w1 = make_float2(cs, sn);
  float2 w2 = cmul(w1, w1);
  float2 w3 = cmul(w2, w1);
  u[1] = cmul(u[1], w1); u[2] = cmul(u[2], w2); u[3] = cmul(u[3], w3);
  fft4<SGN>(u);
}

// ---------------- forward STFT: one block per (n,c,f) frame ----------------
// XCD-chunked remap: hw bid -> w = (bid&7)*300 + (bid>>3); each XCD (bid%8
// heuristic) gets 300 CONSECUTIVE frames of one channel -> the 4x-overlapping
// audio window reads stay in that XCD's L2 (614 KB span) instead of being
// re-fetched by 4 different XCDs.
__global__ __launch_bounds__(256, 6) void stft_kernel(const float* __restrict__ audio,
                                                      float2* __restrict__ X) {
  __shared__ float2 lds[2176];
  int bid = blockIdx.x;
  int w  = (bid & 7) * 300 + (bid >> 3);   // 2400 = 8*300, bijective
  int f  = w % NFR;
  int nc = w / NFR;
  const float* x = audio + (size_t)nc * TLEN;
  int tid = threadIdx.x;
  int base = f * 1024;
  float2 v[8];
#pragma unroll
  for (int r = 0; r < 8; ++r) {
    int k = tid + 256 * r;
    int j0 = 2 * k;
    v[r] = make_float2(reflect_load(x, base + j0)     * winf(j0),
                       reflect_load(x, base + j0 + 1) * winf(j0 + 1));
  }
  fft2048_mid<-1>(lds, v, tid);
  fft2048_last<-1>(lds, tid,        v);
  fft2048_last<-1>(lds, tid + 256,  v + 4);
  __syncthreads();
#pragma unroll
  for (int r = 0; r < 4; ++r) lds[PHYS(tid + 512 * r)] = v[r];
#pragma unroll
  for (int r = 0; r < 4; ++r) lds[PHYS(tid + 256 + 512 * r)] = v[4 + r];
  __syncthreads();
  float2* out = X + ((size_t)nc * NFR + f) * NB;
  float sn0, cs0;
  __sincosf(-PI_F * (float)tid * (1.0f / 2048.0f), &sn0, &cs0);
  float2 ph = make_float2(cs0, sn0);
  const float2 rot = make_float2(0.92387953251128675613f, -0.38268343236508977173f);
#pragma unroll
  for (int r = 0; r < 9; ++r) {
    int k = tid + 256 * r;
    if (k <= 2048) {
      float2 Zk = lds[PHYS(k & 2047)];
      float2 Zm = lds[PHYS((2048 - k) & 2047)];
      float Ex = 0.5f * (Zk.x + Zm.x), Ey = 0.5f * (Zk.y - Zm.y);
      float Dx = 0.5f * (Zk.x - Zm.x), Dy = 0.5f * (Zk.y + Zm.y);
      float Ox = Dy, Oy = -Dx;                       // O = -i*D
      out[k] = make_float2(Ex + Ox * ph.x - Oy * ph.y, Ey + Ox * ph.y + Oy * ph.x);
    }
    ph = cmul(ph, rot);
  }
}

// ------- per-(n,chunk,b) covariance stats (float4/bin) + fused chunk max -------
__global__ __launch_bounds__(256) void stats_kernel(const float2* __restrict__ X,
                                                    float* __restrict__ stats4,
                                                    unsigned int* __restrict__ maxsq) {
  __shared__ unsigned int sm;
  if (threadIdx.x == 0) sm = 0u;
  __syncthreads();
  int b = blockIdx.x * 256 + threadIdx.x;
  bool ok = (b < NB);
  int g = blockIdx.y;                 // n*2 + chunk
  int n = g >> 1, chunk = g & 1;
  int t0 = blockIdx.z * 75;
  const float2* X0 = X + ((size_t)(n * 2 + 0) * NFR + chunk * 300 + t0) * NB + (ok ? b : 0);
  const float2* X1 = X + ((size_t)(n * 2 + 1) * NFR + chunk * 300 + t0) * NB + (ok ? b : 0);
  float s00 = 0.f, s11 = 0.f, sre = 0.f, sim = 0.f, lmax = 0.f;
  if (ok) {
    for (int t = 0; t < 75; ++t) {
      float2 a = X0[(size_t)t * NB];
      float2 c = X1[(size_t)t * NB];
      float pa = a.x * a.x + a.y * a.y;
      float pc = c.x * c.x + c.y * c.y;
      s00 += pa; s11 += pc;
      sre += a.x * c.x + a.y * c.y;
      sim += a.y * c.x - a.x * c.y;
      lmax = fmaxf(lmax, fmaxf(pa, pc));
    }
  }
  atomicMax(&sm, __float_as_uint(lmax));
  __syncthreads();
  if (threadIdx.x == 0) atomicMax(&maxsq[g], sm);
  if (ok) {
    float* sp = stats4 + ((size_t)g * NB + b) * 4;
    unsafeAtomicAdd(sp + 0, s00);
    unsafeAtomicAdd(sp + 1, s11);
    unsafeAtomicAdd(sp + 2, sre);
    unsafeAtomicAdd(sp + 3, sim);
  }
}

// ---------------- alpha_s + K = sum_s alpha per (g,b) ----------------
__global__ __launch_bounds__(256) void alpha_kernel(const float* __restrict__ Wmask,
                                                    const float4* __restrict__ stats4,
                                                    const unsigned int* __restrict__ maxsq,
                                                    float* __restrict__ alpha,
                                                    float* __restrict__ Ksum) {
  int idx = blockIdx.x * 256 + threadIdx.x;
  if (idx >= 4 * NB) return;
  int b = idx % NB;
  int g = idx / NB;
  float ma2 = fmaxf(1.0f, __uint_as_float(maxsq[g]) * 0.01f);   // max_abs^2
  float4 s4 = stats4[(size_t)g * NB + b];
  float P = 0.5f * (s4.x + s4.y) / ma2;
  float K = 0.f;
#pragma unroll
  for (int s = 0; s < 4; ++s) {
    float mv = 1.0f / (1.0f + expf(-Wmask[s * NB + b]));
    float m2 = mv * mv;
    float a = (m2 * m2) / (1e-10f + m2 * P);
    alpha[(size_t)(g * 4 + s) * NB + b] = a;
    K += a;
  }
  Ksum[(size_t)g * NB + b] = K;
}

// ------- Wiener core (s-independent field): Wc[t,c] = p̂ * (G * inv(Cxx) * x)[c] -------
__global__ __launch_bounds__(256) void wiener_kernel(const float2* __restrict__ X,
                                                     const float4* __restrict__ stats4,
                                                     const float* __restrict__ Ksum,
                                                     const unsigned int* __restrict__ maxsq,
                                                     float2* __restrict__ Wc) {
  int idx = blockIdx.x * 256 + threadIdx.x;
  if (idx >= 4 * 300 * NB) return;
  int b = idx % NB;
  int gt = idx / NB;
  int t = gt % 300;
  int g = gt / 300;
  int n = g >> 1, chunk = g & 1;
  int f = chunk * 300 + t;
  float ima2 = 1.0f / fmaxf(1.0f, __uint_as_float(maxsq[g]) * 0.01f);
  float4 s4 = stats4[(size_t)g * NB + b];
  float g00 = s4.x * ima2, g11 = s4.y * ima2, gre = s4.z * ima2, gim = s4.w * ima2;
  float K = Ksum[(size_t)g * NB + b];
  float2 x0 = X[((size_t)(n * 2 + 0) * NFR + f) * NB + b];
  float2 x1 = X[((size_t)(n * 2 + 1) * NFR + f) * NB + b];
  float ph = 0.5f * ((x0.x * x0.x + x0.y * x0.y) + (x1.x * x1.x + x1.y * x1.y)) * ima2;
  float pk = ph * K;
  float M00 = 1e-5f + pk * g00;
  float M11 = 1e-5f + pk * g11;
  float Mre = pk * gre, Mim = pk * gim;                // M01
  float det = M00 * M11 - (Mre * Mre + Mim * Mim);
  float sc = ph / det;
  float u0x = M11 * x0.x - (Mre * x1.x - Mim * x1.y);
  float u0y = M11 * x0.y - (Mre * x1.y + Mim * x1.x);
  float u1x = M00 * x1.x - (Mre * x0.x + Mim * x0.y);
  float u1y = M00 * x1.y - (Mre * x0.y - Mim * x0.x);
  float w0x = g00 * u0x + (gre * u1x - gim * u1y);
  float w0y = g00 * u0y + (gre * u1y + gim * u1x);
  float w1x = (gre * u0x + gim * u0y) + g11 * u1x;
  float w1y = (gre * u0y - gim * u0x) + g11 * u1y;
  float2* out = Wc + ((size_t)(n * NFR + f) * 2) * NB + b;
  out[0]  = make_float2(w0x * sc, w0y * sc);
  out[NB] = make_float2(w1x * sc, w1y * sc);
}

// ---- inverse rFFT per frame + NON-ATOMIC OLA; MODE: 0=store, 1=add, 2=add+finalize ----
// Round-0 proven body. ONE change: XCD-chunked bid remap so the 8 blocks (4 s x 2 c)
// that read the same (n,f) Wc/alpha rows land on the SAME XCD (consecutive dispatch
// slots, shared L2 row fetch) instead of being scattered (plane stride 300 = 4 mod 8).
template<int MODE>
__global__ __launch_bounds__(256, 6) void istft_pass_kernel(const float2* __restrict__ Wc,
                                                            const float* __restrict__ alpha,
                                                            float* __restrict__ accum,
                                                            float* __restrict__ out,
                                                            int pass) {
  __shared__ float2 lds[2176];
  int bid = blockIdx.x;
  int w = (bid & 7) * 300 + (bid >> 3);  // 2400 = 8*300, bijective
  int member = w & 7;                    // (s,c) member within the (n,fi) sharing group
  int grp = w >> 3;                      // 0..299
  int fi = grp % 150;
  int n  = grp / 150;
  int s = member >> 1;
  int c = member & 1;
  int plane = n * 8 + s * 2 + c;         // ((n*4+s)*2+c)
  int f = 4 * fi + pass;
  int g = n * 2 + (f >= 300 ? 1 : 0);
  int tid = threadIdx.x;
  const float2* Wrow = Wc + ((size_t)(n * NFR + f) * 2 + c) * NB;
  const float*  arow = alpha + (size_t)(g * 4 + s) * NB;
  float* acc = accum + (size_t)plane * OLEN + (size_t)f * 1024;

  // Prefetch the OLA read-modify-write inputs before the FFT (addresses known
  // at entry) so the global read latency hides behind the FFT compute.
  // NOTE: needs the 6-wave launch bound; an 8-wave bound caps VGPRs at 64 and
  // forces scratch spills (round-6 regression).
  float2 pre[8];
  if (MODE >= 1) {
#pragma unroll
    for (int half = 0; half < 2; ++half) {
#pragma unroll
      for (int r = 0; r < 4; ++r) {
        int m = tid + 256 * half + 512 * r;
        pre[half * 4 + r] = *(const float2*)&acc[2 * m];
      }
    }
  }

  float2 v[8];
  float sn0, cs0;
  __sincosf(PI_F * (float)tid * (1.0f / 2048.0f), &sn0, &cs0);
  float2 ph = make_float2(cs0, sn0);
  const float2 rot = make_float2(0.92387953251128675613f, 0.38268343236508977173f);
#pragma unroll
  for (int r = 0; r < 8; ++r) {
    int k = tid + 256 * r;
    float ak = arow[k];
    float2 sk = Wrow[k]; sk.x *= ak; sk.y *= ak;
    int rk = 2048 - k;
    float am = arow[rk];
    float2 sv = Wrow[rk]; sv.x *= am; sv.y *= am;
    float Ex = 0.5f * (sk.x + sv.x), Ey = 0.5f * (sk.y - sv.y);
    float Dx = 0.5f * (sk.x - sv.x), Dy = 0.5f * (sk.y + sv.y);
    float Ox = Dx * ph.x - Dy * ph.y, Oy = Dx * ph.y + Dy * ph.x;  // O = D*e^{+i pi k/2048}
    v[r] = make_float2(Ex - Oy, Ey + Ox);                           // Z = E + iO
    ph = cmul(ph, rot);
  }
  fft2048_mid<1>(lds, v, tid);
  float* outp = out + (size_t)plane * TLEN;
  const float scale = 1.0f / 2048.0f;
#pragma unroll
  for (int half = 0; half < 2; ++half) {
    int jj = tid + 256 * half;
    float2 u[4];
    fft2048_last<1>(lds, jj, u);
#pragma unroll
    for (int r = 0; r < 4; ++r) {
      int m = jj + 512 * r;
      int j0 = 2 * m;
      float2 val = make_float2(u[r].x * scale * winf(j0),
                               u[r].y * scale * winf(j0 + 1));
      float2* p = (float2*)&acc[j0];
      if (MODE == 0) {
        *p = val;
      } else if (MODE == 1) {
        float2 o = pre[half * 4 + r];
        val.x += o.x; val.y += o.y;
        *p = val;
      } else {
        int gm = f * 1024 + j0;                       // accum coordinate (even)
        if (gm < 615424) {                            // out covers [2048, 615424)
          float2 o = pre[half * 4 + r];
          val.x += o.x; val.y += o.y;
          float i0, i1;
          if (gm >= 3072 && gm + 1 < 614400) {        // interior: wsum == 1.5
            i0 = 0.66666666666666667f; i1 = i0;
          } else {
            i0 = 1.0f / wsum_at(gm); i1 = 1.0f / wsum_at(gm + 1);
          }
          float2* po = (float2*)&outp[gm - 2048];
          *po = make_float2(val.x * i0, val.y * i1);
        }
      }
    }
  }
  if (MODE == 0 && fi == 149) {
    // zero the plane tail [614400, OLEN) not covered by class-0 frames
    float* tail = accum + (size_t)plane * OLEN + 614400;
    for (int i = tid; i < OLEN - 614400; i += 256) tail[i] = 0.f;
  }
  if (MODE == 2 && fi == 0) {
    // finalize head samples m in [2048, 3072): complete after pass 2
    float* accp = accum + (size_t)plane * OLEN;
    for (int m = 2048 + tid; m < 3072; m += 256) {
      outp[m - 2048] = accp[m] / wsum_at(m);
    }
  }
}

extern "C" void kernel_launch(void* const* d_in, const int* in_sizes, int n_in,
                              void* d_out, int out_size, void* d_ws, size_t ws_size,
                              hipStream_t stream) {
  const float* audio = (const float*)d_in[0];
  const float* Wmask = (const float*)d_in[1];
  float* out = (float*)d_out;

  // layout: [stats4 131136 | maxsq 64] (zeroed) | X 39,340,800 | Wc 39,340,800 |
  //         accum 39,518,208 | alpha 131,136 | Ksum 32,784
  char* ws = (char*)d_ws;
  const size_t off_stats4 = 0;
  const size_t off_maxsq  = 131136;
  const size_t zero_span  = 131200;
  const size_t off_X      = zero_span;
  const size_t off_Wc     = off_X + 39340800;
  const size_t off_accum  = off_Wc + 39340800;
  const size_t off_alpha  = off_accum + 39518208;
  const size_t off_Ksum   = off_alpha + 131136;

  float*        stats4f = (float*)(ws + off_stats4);
  float4*       stats4  = (float4*)(ws + off_stats4);
  unsigned int* maxsq   = (unsigned int*)(ws + off_maxsq);
  float2*       X       = (float2*)(ws + off_X);
  float2*       Wc      = (float2*)(ws + off_Wc);
  float*        accum   = (float*)(ws + off_accum);
  float*        alpha   = (float*)(ws + off_alpha);
  float*        Ksum    = (float*)(ws + off_Ksum);

  hipMemsetAsync(ws, 0, zero_span, stream);

  stft_kernel<<<2400, 256, 0, stream>>>(audio, X);
  stats_kernel<<<dim3(9, 4, 4), 256, 0, stream>>>(X, stats4f, maxsq);
  alpha_kernel<<<(4 * NB + 255) / 256, 256, 0, stream>>>(Wmask, stats4, maxsq, alpha, Ksum);
  wiener_kernel<<<(4 * 300 * NB + 255) / 256, 256, 0, stream>>>(X, stats4, Ksum, maxsq, Wc);
  istft_pass_kernel<0><<<2400, 256, 0, stream>>>(Wc, alpha, accum, out, 0);
  istft_pass_kernel<1><<<2400, 256, 0, stream>>>(Wc, alpha, accum, out, 1);
  istft_pass_kernel<1><<<2400, 256, 0, stream>>>(Wc, alpha, accum, out, 2);
  istft_pass_kernel<2><<<2400, 256, 0, stream>>>(Wc, alpha, accum, out, 3);
}